// Round 13
// baseline (105.664 us; speedup 1.0000x reference)
//
#include <hip/hip_runtime.h>
#include <stdint.h>

#define T_LEN 512
#define I_LEN 5
#define CHUNK 8                    // timesteps per staged chunk
#define NCHUNK 64                  // T_LEN / CHUNK

// __fp16 matches __builtin_amdgcn_cvt_pkrtz's return element type
typedef __fp16 h2_t __attribute__((ext_vector_type(2)));
typedef __fp16 h4_t __attribute__((ext_vector_type(4)));
typedef float  f4v  __attribute__((ext_vector_type(4)));

// global -> LDS direct DMA, 16B/lane, LDS dst = wave-uniform base + lane*16
__device__ __forceinline__ void gload_lds16(const float* g, float* l) {
    auto gp = reinterpret_cast<const __attribute__((address_space(1))) float*>(
        reinterpret_cast<uintptr_t>(g));
    auto lp = reinterpret_cast<__attribute__((address_space(3))) float*>(
        reinterpret_cast<uintptr_t>(l));
    __builtin_amdgcn_global_load_lds(gp, lp, 16, 0, 0);
}

// Volatile asm ds_read_b128: cannot be sunk or split (r11 lesson).
#define DSR(dst, addr, OFFSTR)                                              \
    asm volatile("ds_read_b128 %0, %1 offset:" OFFSTR                       \
                 : "=v"(dst) : "v"(addr))

#define DSR10(q, addr)                                                      \
    do {                                                                    \
        DSR((q)[0], (addr), "0");   DSR((q)[1], (addr), "16");              \
        DSR((q)[2], (addr), "32");  DSR((q)[3], (addr), "48");              \
        DSR((q)[4], (addr), "64");  DSR((q)[5], (addr), "80");              \
        DSR((q)[6], (addr), "96");  DSR((q)[7], (addr), "112");             \
        DSR((q)[8], (addr), "128"); DSR((q)[9], (addr), "144");             \
    } while (0)

#define WAIT_LGKM0()                                                        \
    do {                                                                    \
        asm volatile("s_waitcnt lgkmcnt(0)" ::: "memory");                  \
        __builtin_amdgcn_sched_barrier(0);                                  \
    } while (0)

#define WAIT_VM(N)                                                          \
    asm volatile("s_waitcnt vmcnt(" #N ")" ::: "memory")

// Component extract with compile-time-constant idx (free after unroll).
__device__ __forceinline__ float f4_at(const float4* b, int idx) {
    const float4 v = b[idx >> 2];
    switch (idx & 3) {
        case 0: return v.x;
        case 1: return v.y;
        case 2: return v.z;
        default: return v.w;
    }
}

// Off-chain prep for step s: B1 fragment from q, xw[s] = SC*W_ih*x + cbias'.
__device__ __forceinline__ void prep_step(const float4* __restrict__ q, int s,
                                          h4_t aih, f4v cbias,
                                          f4v* __restrict__ xw) {
    const float e0 = f4_at(q, 5 * s + 0);
    const float e1 = f4_at(q, 5 * s + 1);
    const float e2 = f4_at(q, 5 * s + 2);
    const float e3 = f4_at(q, 5 * s + 3);
    h2_t lo = __builtin_amdgcn_cvt_pkrtz(e0, e1);
    h2_t hi = __builtin_amdgcn_cvt_pkrtz(e2, e3);
    h4_t b1 = __builtin_shufflevector(lo, hi, 0, 1, 2, 3);
    xw[s] = __builtin_amdgcn_mfma_f32_16x16x16f16(aih, b1, cbias, 0, 0, 0);
}

// Serial chain step, r-state form (verified r12): zs = A'*r + xw;
// r' = rcp(exp2(zs)+1).  A' = -2*SC*W_hh; xw includes SC*(b + W_hh*1).
__device__ __forceinline__ void chain_step(h4_t& bh, h4_t ahh2, f4v xws) {
    f4v acc = __builtin_amdgcn_mfma_f32_16x16x16f16(ahh2, bh, xws, 0, 0, 0);
    const float r0 = __builtin_amdgcn_rcpf(__builtin_exp2f(acc[0]) + 1.0f);
    const float r1 = __builtin_amdgcn_rcpf(__builtin_exp2f(acc[1]) + 1.0f);
    const float r2 = __builtin_amdgcn_rcpf(__builtin_exp2f(acc[2]) + 1.0f);
    const float r3 = __builtin_amdgcn_rcpf(__builtin_exp2f(acc[3]) + 1.0f);
    h2_t blo = __builtin_amdgcn_cvt_pkrtz(r0, r1);
    h2_t bhi = __builtin_amdgcn_cvt_pkrtz(r2, r3);
    bh = __builtin_shufflevector(blo, bhi, 0, 1, 2, 3);
}

// r13: 8 waves/block (512 thr) -> 2 chain-waves per SIMD so the HW scheduler
// fills one chain's dependency stalls with the other wave's work.
// Per-wave LDS shrinks to a 2-slot ping-pong (6 KB) so 8 waves fit in 48 KB.
__global__ __launch_bounds__(512) void rnn_m2o_kernel(
    const float* __restrict__ x, const float* __restrict__ W_ih,
    const float* __restrict__ W_hh, const float* __restrict__ b_ih,
    const float* __restrict__ b_hh, const float* __restrict__ W_fc,
    const float* __restrict__ b_fc, float* __restrict__ out)
{
    const int tid  = threadIdx.x;
    const int wave = tid >> 6;         // 0..7
    const int lane = tid & 63;
    const int g    = lane >> 4;        // lane-group 0..3
    const int bcol = lane & 15;        // batch column (n of B/D), A row (m)
    const int bb   = (blockIdx.x * 8 + wave) * 16;  // wave's first batch

    __shared__ float lds[8 * 1536];    // 8 waves x 2 slots x 3072 B = 48 KB
    float* ldsW = &lds[wave * 1536];

    const float SC = 2.8853900817779268f;   // 2*log2(e)

    // Fragments (r9-verified mapping). A: m=lane&15, k=4g+i; C/D row=4g+i.
    h4_t ahh2, aih;
    f4v  cbias, wfc4;
#pragma unroll
    for (int i = 0; i < 4; ++i) {
        const int k = 4 * g + i;
        ahh2[i]  = (__fp16)(-2.0f * SC * W_hh[bcol * 16 + k]);
        aih[i]   = (__fp16)((k < I_LEN) ? W_ih[bcol * I_LEN + k] * SC : 0.0f);
        float rowsum = 0.0f;
        for (int m = 0; m < 16; ++m) rowsum += W_hh[k * 16 + m];
        cbias[i] = (b_ih[k] + b_hh[k] + rowsum) * SC;
        wfc4[i]  = -2.0f * W_fc[k];
    }
    float wfcsum = 0.0f;
    for (int jj = 0; jj < 16; ++jj) wfcsum += W_fc[jj];
    const float bfcP = b_fc[0] + wfcsum;

    // Staging map (r9-verified): s = 64L + lane = 11*b + i; batch b at dword
    // 44b within the slot.
    const float* gsrc[3];
#pragma unroll
    for (int L = 0; L < 3; ++L) {
        const int s = 64 * L + lane;
        const int sb = s / 11, si = s % 11;
        const bool real = (s < 176) && (si < 10);
        gsrc[L] = x + (size_t)(bb + (real ? sb : 0)) * (T_LEN * I_LEN)
                    + (real ? si * 4 : 0);
    }

#define STAGE(n_)                                                           \
    do {                                                                    \
        const int off_ = ((n_) & (NCHUNK - 1)) * (CHUNK * I_LEN);           \
        float* dst_ = ldsW + ((n_) & 1) * 768;                              \
        gload_lds16(gsrc[0] + off_, dst_);                                  \
        gload_lds16(gsrc[1] + off_, dst_ + 256);                            \
        gload_lds16(gsrc[2] + off_, dst_ + 512);                            \
    } while (0)

    // Read base: my batch row (176B stride); odd lane-groups +16B (x4-shift).
    const uint32_t rbase = (uint32_t)(uintptr_t)ldsW
                         + (uint32_t)(bcol * 176 + (g & 1) * 16);

    h4_t bh;                           // r-state; r_0 = 0.5 (h_0 = 0)
    bh[0] = (__fp16)0.5f; bh[1] = (__fp16)0.5f;
    bh[2] = (__fp16)0.5f; bh[3] = (__fp16)0.5f;

    f4v  xwA[8], xwB[8];
    float4 q[10];

    // Prologue: stage chunk 0, read+prep it, stage chunk 1.
    STAGE(0);
    WAIT_VM(0);                        // chunk 0 landed
    DSR10(q, rbase);
    WAIT_LGKM0();
#pragma unroll
    for (int s = 0; s < 8; ++s) prep_step(q, s, aih, cbias, xwA);
    STAGE(1);

    for (int n = 0; n < NCHUNK; n += 2) {
        {   // even region: chain chunk n (xwA); DSR+prep chunk n+1 -> xwB
            WAIT_VM(0);                // chunk n+1 landed (staged last region)
            DSR10(q, rbase + (uint32_t)(((n + 1) & 1) * 3072));
            WAIT_LGKM0();
            STAGE(n + 2);              // into chunk n's slot (q consumed)
#pragma unroll
            for (int s = 0; s < 8; ++s) {
                chain_step(bh, ahh2, xwA[s]);
                prep_step(q, s, aih, cbias, xwB);
            }
        }
        {   // odd region: chain chunk n+1 (xwB); DSR+prep chunk n+2 -> xwA
            WAIT_VM(0);                // chunk n+2 landed
            DSR10(q, rbase + (uint32_t)(((n + 2) & 1) * 3072));
            WAIT_LGKM0();
            STAGE(n + 3);
#pragma unroll
            for (int s = 0; s < 8; ++s) {
                chain_step(bh, ahh2, xwB[s]);
                prep_step(q, s, aih, cbias, xwA);
            }
        }
    }
    WAIT_VM(0);                        // drain tail DMAs

    // fc + sigmoid (folded, r12-verified): z = sum (-2 wfc_j) r_j + bfc'
    float p = (float)bh[0] * wfc4[0] + (float)bh[1] * wfc4[1]
            + (float)bh[2] * wfc4[2] + (float)bh[3] * wfc4[3];
    p += __shfl_xor(p, 16);
    p += __shfl_xor(p, 32);
    if (lane < 16) {
        const float z = p + bfcP;
        out[bb + lane] = __builtin_amdgcn_rcpf(
            1.0f + __builtin_exp2f(z * -1.4426950408889634f));
    }
#undef STAGE
}

extern "C" void kernel_launch(void* const* d_in, const int* in_sizes, int n_in,
                              void* d_out, int out_size, void* d_ws, size_t ws_size,
                              hipStream_t stream) {
    const float* x    = (const float*)d_in[0];
    const float* W_ih = (const float*)d_in[1];
    const float* W_hh = (const float*)d_in[2];
    const float* b_ih = (const float*)d_in[3];
    const float* b_hh = (const float*)d_in[4];
    const float* W_fc = (const float*)d_in[5];
    const float* b_fc = (const float*)d_in[6];
    float* out = (float*)d_out;

    const int B = in_sizes[0] / (T_LEN * I_LEN);   // 8192
    const int blocks = B / (16 * 8);               // 8 chain-waves per block
    rnn_m2o_kernel<<<blocks, 512, 0, stream>>>(x, W_ih, W_hh, b_ih, b_hh,
                                               W_fc, b_fc, out);
}

// Round 16
// 67.141 us; speedup vs baseline: 1.5738x; 1.5738x over previous
//
#include <hip/hip_runtime.h>
#include <stdint.h>

#define T_LEN 512
#define I_LEN 5
#define CHUNK 8                    // timesteps per staged chunk
#define NCHUNK 64                  // T_LEN / CHUNK

// __fp16 matches __builtin_amdgcn_cvt_pkrtz's return element type
typedef __fp16 h2_t __attribute__((ext_vector_type(2)));
typedef __fp16 h4_t __attribute__((ext_vector_type(4)));
typedef float  f4v  __attribute__((ext_vector_type(4)));

// global -> LDS direct DMA, 16B/lane, LDS dst = wave-uniform base + lane*16
__device__ __forceinline__ void gload_lds16(const float* g, float* l) {
    auto gp = reinterpret_cast<const __attribute__((address_space(1))) float*>(
        reinterpret_cast<uintptr_t>(g));
    auto lp = reinterpret_cast<__attribute__((address_space(3))) float*>(
        reinterpret_cast<uintptr_t>(l));
    __builtin_amdgcn_global_load_lds(gp, lp, 16, 0, 0);
}

// Volatile asm ds_read_b128: cannot be sunk or split (r11 lesson).
#define DSR(dst, addr, OFFSTR)                                              \
    asm volatile("ds_read_b128 %0, %1 offset:" OFFSTR                       \
                 : "=v"(dst) : "v"(addr))

#define DSR10(q, addr)                                                      \
    do {                                                                    \
        DSR((q)[0], (addr), "0");   DSR((q)[1], (addr), "16");              \
        DSR((q)[2], (addr), "32");  DSR((q)[3], (addr), "48");              \
        DSR((q)[4], (addr), "64");  DSR((q)[5], (addr), "80");              \
        DSR((q)[6], (addr), "96");  DSR((q)[7], (addr), "112");             \
        DSR((q)[8], (addr), "128"); DSR((q)[9], (addr), "144");             \
    } while (0)

#define WAIT_LGKM0()                                                        \
    do {                                                                    \
        asm volatile("s_waitcnt lgkmcnt(0)" ::: "memory");                  \
        __builtin_amdgcn_sched_barrier(0);                                  \
    } while (0)

#define WAIT_VM(N)                                                          \
    asm volatile("s_waitcnt vmcnt(" #N ")" ::: "memory")

// Component extract with compile-time-constant idx (free after unroll).
__device__ __forceinline__ float f4_at(const float4* b, int idx) {
    const float4 v = b[idx >> 2];
    switch (idx & 3) {
        case 0: return v.x;
        case 1: return v.y;
        case 2: return v.z;
        default: return v.w;
    }
}

// Padé/continued-fraction tanh (4-term), |z| clamped to 5:
//   tanh z ~= z*(945 + 105 t + t^2) / (945 + 420 t + 15 t^2),  t = z^2
// max err: 5.7e-4 @2, 1.1e-3 @3.5, 2.3e-3 @4, 7.5e-3 @5  (thr 1.41e-2).
// ONE transcendental (rcp) per element vs exp2+rcp before.
__device__ __forceinline__ float tanh_pade(float zin) {
    const float z = fminf(fmaxf(zin, -5.0f), 5.0f);
    const float t = z * z;
    const float np = __builtin_fmaf(t, t + 105.0f, 945.0f);
    const float dp = __builtin_fmaf(t, __builtin_fmaf(t, 15.0f, 420.0f),
                                    945.0f);
    return (z * np) * __builtin_amdgcn_rcpf(dp);
}

// Off-chain prep for step s: B1 fragment from q, xw[s] = W_ih*x + bias.
// (structure verified r9-r12; SC fold removed with the exp2 form)
__device__ __forceinline__ void prep_step(const float4* __restrict__ q, int s,
                                          h4_t aih, f4v cbias,
                                          f4v* __restrict__ xw) {
    const float e0 = f4_at(q, 5 * s + 0);
    const float e1 = f4_at(q, 5 * s + 1);
    const float e2 = f4_at(q, 5 * s + 2);
    const float e3 = f4_at(q, 5 * s + 3);
    h2_t lo = __builtin_amdgcn_cvt_pkrtz(e0, e1);
    h2_t hi = __builtin_amdgcn_cvt_pkrtz(e2, e3);
    h4_t b1 = __builtin_shufflevector(lo, hi, 0, 1, 2, 3);
    xw[s] = __builtin_amdgcn_mfma_f32_16x16x16f16(aih, b1, cbias, 0, 0, 0);
}

// Serial chain step, plain h-state: acc = W_hh*h + xw; h' = tanh_pade(acc).
// (D-grouping == B-grouping invariant verified r9: tanh(D) is next B frag.)
__device__ __forceinline__ void chain_step(h4_t& bh, h4_t ahh, f4v xws) {
    f4v acc = __builtin_amdgcn_mfma_f32_16x16x16f16(ahh, bh, xws, 0, 0, 0);
    const float h0 = tanh_pade(acc[0]);
    const float h1 = tanh_pade(acc[1]);
    const float h2 = tanh_pade(acc[2]);
    const float h3 = tanh_pade(acc[3]);
    h2_t blo = __builtin_amdgcn_cvt_pkrtz(h0, h1);
    h2_t bhi = __builtin_amdgcn_cvt_pkrtz(h2, h3);
    bh = __builtin_shufflevector(blo, bhi, 0, 1, 2, 3);
}

__global__ __launch_bounds__(64) void rnn_m2o_kernel(
    const float* __restrict__ x, const float* __restrict__ W_ih,
    const float* __restrict__ W_hh, const float* __restrict__ b_ih,
    const float* __restrict__ b_hh, const float* __restrict__ W_fc,
    const float* __restrict__ b_fc, float* __restrict__ out)
{
    const int lane = threadIdx.x;      // one wave per block
    const int g    = lane >> 4;        // lane-group 0..3
    const int bcol = lane & 15;        // batch column (n of B/D), A row (m)
    const int bb   = blockIdx.x * 16;  // first batch of this wave

    __shared__ float lds[4 * 768];     // 4 slots x 3072 B (r12-verified)

    // Fragments (r9-verified mapping). A: m=lane&15, k=4g+i; C/D row=4g+i.
    h4_t ahh, aih;
    f4v  cbias, wfc4;
#pragma unroll
    for (int i = 0; i < 4; ++i) {
        const int k = 4 * g + i;
        ahh[i]   = (__fp16)W_hh[bcol * 16 + k];
        aih[i]   = (__fp16)((k < I_LEN) ? W_ih[bcol * I_LEN + k] : 0.0f);
        cbias[i] = b_ih[k] + b_hh[k];
        wfc4[i]  = W_fc[k];
    }
    const float bfc = b_fc[0];

    // Staging map (r9-verified): s = 64L + lane = 11*b + i; batch b at dword
    // 44b within the slot.
    const float* gsrc[3];
#pragma unroll
    for (int L = 0; L < 3; ++L) {
        const int s = 64 * L + lane;
        const int sb = s / 11, si = s % 11;
        const bool real = (s < 176) && (si < 10);
        gsrc[L] = x + (size_t)(bb + (real ? sb : 0)) * (T_LEN * I_LEN)
                    + (real ? si * 4 : 0);
    }

#define STAGE(n_)                                                           \
    do {                                                                    \
        const int off_ = ((n_) & (NCHUNK - 1)) * (CHUNK * I_LEN);           \
        float* dst_ = &lds[((n_) & 3) * 768];                               \
        gload_lds16(gsrc[0] + off_, dst_);                                  \
        gload_lds16(gsrc[1] + off_, dst_ + 256);                            \
        gload_lds16(gsrc[2] + off_, dst_ + 512);                            \
    } while (0)

    // Read base: batch row (176B stride); odd lane-groups +16B (x4-shift).
    const uint32_t rbase = (uint32_t)(uintptr_t)&lds[0]
                         + (uint32_t)(bcol * 176 + (g & 1) * 16);

    h4_t bh = (h4_t)0;                 // h_0 = 0

    f4v  xwA[8], xwB[8];
    float4 qU[10], qV[10];

    // Prologue (r12-verified): chains n | preps n+1 (qU) | DSRs n+2 (qV).
    STAGE(0); STAGE(1); STAGE(2);      // 9 DMAs in flight
    WAIT_VM(6);                        // chunk 0 landed
    DSR10(qV, rbase);                  // q_0 (temp in qV)
    WAIT_LGKM0();
#pragma unroll
    for (int s = 0; s < 8; ++s) prep_step(qV, s, aih, cbias, xwA);  // xw_0
    STAGE(3);
    WAIT_VM(6);                        // chunk 1 landed
    DSR10(qU, rbase + 1 * 3072);       // q_1
    WAIT_LGKM0();

    for (int n = 0; n < NCHUNK; n += 2) {
        {   // even region: chain n (xwA) ∥ prep n+1 (qU -> xwB); DSR n+2->qV
            STAGE(n + 4);
            WAIT_VM(6);                // chunk n+2 landed
            DSR10(qV, rbase + (uint32_t)(((n + 2) & 3) * 3072));
#pragma unroll
            for (int s = 0; s < 8; ++s) {
                chain_step(bh, ahh, xwA[s]);
                prep_step(qU, s, aih, cbias, xwB);
            }
            WAIT_LGKM0();
        }
        {   // odd region: chain n+1 (xwB) ∥ prep n+2 (qV -> xwA); DSR n+3->qU
            STAGE(n + 5);
            WAIT_VM(6);                // chunk n+3 landed
            DSR10(qU, rbase + (uint32_t)(((n + 3) & 3) * 3072));
#pragma unroll
            for (int s = 0; s < 8; ++s) {
                chain_step(bh, ahh, xwB[s]);
                prep_step(qV, s, aih, cbias, xwA);
            }
            WAIT_LGKM0();
        }
    }
    WAIT_VM(0);                        // drain tail DMAs

    // fc + sigmoid: unpack final h (f16, same values the recurrence used).
    float p = (float)bh[0] * wfc4[0] + (float)bh[1] * wfc4[1]
            + (float)bh[2] * wfc4[2] + (float)bh[3] * wfc4[3];
    p += __shfl_xor(p, 16);
    p += __shfl_xor(p, 32);
    if (lane < 16) {
        const float z = p + bfc;
        out[bb + lane] = __builtin_amdgcn_rcpf(
            1.0f + __builtin_exp2f(z * -1.4426950408889634f));
    }
#undef STAGE
}

extern "C" void kernel_launch(void* const* d_in, const int* in_sizes, int n_in,
                              void* d_out, int out_size, void* d_ws, size_t ws_size,
                              hipStream_t stream) {
    const float* x    = (const float*)d_in[0];
    const float* W_ih = (const float*)d_in[1];
    const float* W_hh = (const float*)d_in[2];
    const float* b_ih = (const float*)d_in[3];
    const float* b_hh = (const float*)d_in[4];
    const float* W_fc = (const float*)d_in[5];
    const float* b_fc = (const float*)d_in[6];
    float* out = (float*)d_out;

    const int B = in_sizes[0] / (T_LEN * I_LEN);   // 8192
    const int blocks = B / 16;                     // 16 batches per wave
    rnn_m2o_kernel<<<blocks, 64, 0, stream>>>(x, W_ih, W_hh, b_ih, b_hh,
                                              W_fc, b_fc, out);
}